// Round 19
// baseline (120.122 us; speedup 1.0000x reference)
//
#include <hip/hip_runtime.h>
#include <hip/hip_bf16.h>
#include <stdint.h>

typedef unsigned short bfu;
typedef __attribute__((ext_vector_type(8))) short short8;
typedef __attribute__((ext_vector_type(4))) float f32x4;

#define LOG2E 1.4426950408889634f

__device__ __forceinline__ bfu f2bf(float f) {
  union { float f; uint32_t u; } v; v.f = f;
  uint32_t r = (v.u + 0x7fffu + ((v.u >> 16) & 1u)) >> 16;
  return (bfu)r;
}

__device__ __forceinline__ void gload16(const void* g, void* l) {
  __builtin_amdgcn_global_load_lds((const __attribute__((address_space(1))) void*)g,
                                   (__attribute__((address_space(3))) void*)l, 16, 0, 0);
}

// ---------------- prep: conv x, conv ctx, transpose 4 weights -- one launch [proven] ----------------
__device__ __forceinline__ void conv_body(const float* __restrict__ in, bfu* __restrict__ out,
                                          int i) {
  const float4* p = (const float4*)in + (size_t)i * 2;
  float4 a = p[0], b = p[1];
  union { bfu h[8]; uint4 v; } o;
  o.h[0] = f2bf(a.x); o.h[1] = f2bf(a.y); o.h[2] = f2bf(a.z); o.h[3] = f2bf(a.w);
  o.h[4] = f2bf(b.x); o.h[5] = f2bf(b.y); o.h[6] = f2bf(b.z); o.h[7] = f2bf(b.w);
  ((uint4*)out)[i] = o.v;
}

__device__ __forceinline__ void trans_body(const float* __restrict__ W, bfu* __restrict__ WT,
                                           int Kd, int n0, int k0) {
  __shared__ float tile[32][33];
  const int tx = threadIdx.x & 31, ty = threadIdx.x >> 5;
#pragma unroll
  for (int i = 0; i < 32; i += 8)
    tile[ty + i][tx] = W[(size_t)(k0 + ty + i) * 1024 + n0 + tx];
  __syncthreads();
#pragma unroll
  for (int i = 0; i < 32; i += 8)
    WT[(size_t)(n0 + ty + i) * Kd + k0 + tx] = f2bf(tile[tx][ty + i]);
}

__global__ __launch_bounds__(256) void prep_kernel(
    const float* __restrict__ x, const float* __restrict__ ctx,
    const float* __restrict__ Wq, const float* __restrict__ Wk,
    const float* __restrict__ Wv, const float* __restrict__ Wo,
    bfu* xb, bfu* ctxb, bfu* WTq, bfu* WTk, bfu* WTv, bfu* WTo) {
  int b = blockIdx.x;
  if (b < 1024)       conv_body(x, xb, b * 256 + threadIdx.x);
  else if (b < 1792)  conv_body(ctx, ctxb, (b - 1024) * 256 + threadIdx.x);
  else if (b < 2816) { b -= 1792; trans_body(Wq, WTq, 1024, (b & 31) * 32, (b >> 5) * 32); }
  else if (b < 3584) { b -= 2816; trans_body(Wk, WTk, 768, (b & 31) * 32, (b >> 5) * 32); }
  else if (b < 4352) { b -= 3584; trans_body(Wv, WTv, 768, (b & 31) * 32, (b >> 5) * 32); }
  else               { b -= 4352; trans_body(Wo, WTo, 1024, (b & 31) * 32, (b >> 5) * 32); }
}

// ---------------- 128x128 GEMM body (r8/r17-PROVEN), BK=32, async dbuf ----------------
typedef bfu Tile128[2][4][128][8];

__device__ __forceinline__ void gemm128_body(Tile128& As2, Tile128& Bs2,
    const bfu* __restrict__ A, const bfu* __restrict__ BT,
    bfu* __restrict__ Cb, int N, int K, float scale, int m0, int n0) {
  const int tid = threadIdx.x, lane = tid & 63, wave = tid >> 6;
  const int g = lane >> 4, c = lane & 15;
  const int wm = (wave >> 1) * 64, wn = (wave & 1) * 64;
  const int nt = K / 32;

  auto stage = [&](int buf, int kt) {
#pragma unroll
    for (int u = 0; u < 4; ++u) {
      int idx = wave * 4 + u;
      if (idx < 8) {
        int kg = idx & 3, rb = idx >> 2;
        gload16(&A[(size_t)(m0 + rb * 64 + lane) * K + kt + kg * 8], &As2[buf][kg][rb * 64][0]);
      } else {
        int kg = (idx - 8) & 3, rb = (idx - 8) >> 2;
        gload16(&BT[(size_t)(n0 + rb * 64 + lane) * K + kt + kg * 8], &Bs2[buf][kg][rb * 64][0]);
      }
    }
  };

  f32x4 acc[4][4] = {};
  stage(0, 0);
  for (int t = 0; t < nt; ++t) {
    __syncthreads();
    if (t + 1 < nt) stage((t + 1) & 1, (t + 1) * 32);
    const int b = t & 1;
    short8 af[4], bfr[4];
#pragma unroll
    for (int i = 0; i < 4; ++i) {
      af[i]  = *(const short8*)&As2[b][g][wm + i * 16 + c][0];
      bfr[i] = *(const short8*)&Bs2[b][g][wn + i * 16 + c][0];
    }
#pragma unroll
    for (int i = 0; i < 4; ++i)
#pragma unroll
      for (int j = 0; j < 4; ++j)
        acc[i][j] = __builtin_amdgcn_mfma_f32_16x16x32_bf16(af[i], bfr[j], acc[i][j], 0, 0, 0);
  }
#pragma unroll
  for (int i = 0; i < 4; ++i)
#pragma unroll
    for (int j = 0; j < 4; ++j) {
      int row = m0 + wm + i * 16 + g * 4;
      int col = n0 + wn + j * 16 + c;
#pragma unroll
      for (int r = 0; r < 4; ++r)
        Cb[(size_t)(row + r) * N + col] = f2bf(acc[i][j][r] * scale);
    }
}

// fused Q/K/V projections at 128x128: 384 blocks  [r17-proven]
__global__ __launch_bounds__(256) void gemm3_kernel(
    const bfu* __restrict__ xb, const bfu* __restrict__ WTq, bfu* __restrict__ Qb,
    const bfu* __restrict__ ctxb, const bfu* __restrict__ WTk, bfu* __restrict__ Kb,
    const bfu* __restrict__ WTv, bfu* __restrict__ Vtb) {
  __shared__ alignas(16) bfu As2[2][4][128][8];
  __shared__ alignas(16) bfu Bs2[2][4][128][8];
  int bid = blockIdx.x;
  if (bid < 128)
    gemm128_body(As2, Bs2, xb, WTq, Qb, 1024, 1024, 0.125f * LOG2E, (bid >> 3) * 128, (bid & 7) * 128);
  else if (bid < 256) {
    int r = bid - 128;
    gemm128_body(As2, Bs2, ctxb, WTk, Kb, 1024, 768, 1.0f, (r >> 3) * 128, (r & 7) * 128);
  } else {  // V^T = Wv^T @ ctx^T : A = WTv (1024x768), BT = ctxb (2048x768)
    int r = bid - 256;
    gemm128_body(As2, Bs2, WTv, ctxb, Vtb, 2048, 768, 1.0f, (r >> 4) * 128, (r & 15) * 128);
  }
}

// ---------------- 128x64 GEMM body [proven verbatim] -- output projection ----------------
typedef bfu AsArr[2][4][128][8];
typedef bfu BsArr[2][4][64][8];

__device__ __forceinline__ void gemm_body(AsArr& As2, BsArr& Bs2,
    const bfu* __restrict__ A, const bfu* __restrict__ BT,
    bfu* __restrict__ Cb, float* __restrict__ Cf,
    int N, int K, float scale, int m0, int n0) {
  const int tid = threadIdx.x, lane = tid & 63, wave = tid >> 6;
  const int g = lane >> 4, c = lane & 15;
  const int wm = wave * 32;
  const int nt = K / 32;

  auto stage = [&](int buf, int kt) {
#pragma unroll
    for (int u = 0; u < 3; ++u) {
      int idx = wave * 3 + u;
      if (idx < 8) {
        int g2 = idx & 3, rb = idx >> 2;
        gload16(&A[(size_t)(m0 + rb * 64 + lane) * K + kt + g2 * 8], &As2[buf][g2][rb * 64][0]);
      } else {
        int g2 = idx - 8;
        gload16(&BT[(size_t)(n0 + lane) * K + kt + g2 * 8], &Bs2[buf][g2][0][0]);
      }
    }
  };

  f32x4 acc[2][4] = {};
  stage(0, 0);
  for (int t = 0; t < nt; ++t) {
    __syncthreads();
    if (t + 1 < nt) stage((t + 1) & 1, (t + 1) * 32);
    const int b = t & 1;
    short8 af[2], bfr[4];
#pragma unroll
    for (int i = 0; i < 2; ++i) af[i] = *(const short8*)&As2[b][g][wm + i * 16 + c][0];
#pragma unroll
    for (int j = 0; j < 4; ++j) bfr[j] = *(const short8*)&Bs2[b][g][j * 16 + c][0];
#pragma unroll
    for (int i = 0; i < 2; ++i)
#pragma unroll
      for (int j = 0; j < 4; ++j)
        acc[i][j] = __builtin_amdgcn_mfma_f32_16x16x32_bf16(af[i], bfr[j], acc[i][j], 0, 0, 0);
  }
#pragma unroll
  for (int i = 0; i < 2; ++i)
#pragma unroll
    for (int j = 0; j < 4; ++j) {
      int row = m0 + wm + i * 16 + g * 4;
      int col = n0 + j * 16 + c;
#pragma unroll
      for (int r = 0; r < 4; ++r) {
        float v = acc[i][j][r] * scale;
        if (Cb) Cb[(size_t)(row + r) * N + col] = f2bf(v);
        else    Cf[(size_t)(row + r) * N + col] = v;
      }
    }
}

// output projection: f32 out, 256 blocks  [proven]
__global__ __launch_bounds__(256) void gemmo_kernel(const bfu* __restrict__ AO,
                                                    const bfu* __restrict__ WTo,
                                                    float* __restrict__ out) {
  __shared__ alignas(16) bfu As2[2][4][128][8];
  __shared__ alignas(16) bfu Bs2[2][4][64][8];
  int bid = blockIdx.x;
  gemm_body(As2, Bs2, AO, WTo, nullptr, out, 1024, 1024, 1.0f, (bid >> 4) * 128, (bid & 15) * 64);
}

// ---------------- flash attention: r18 structure; staggered 2K+2V buffers, &1 rotation ----------------
// Stagger: iter t issues stageK(t+1) and stageV(t). Disjointness:
//   K: qk(t) reads Ks[t&1]; stageK writes Ks[(t+1)&1]  -> disjoint.
//   V: pv(t-1) reads Vs[(t-1)&1]; stageV writes Vs[t&1] -> disjoint.
// Both staged one full iteration before their drain barrier (same cover as
// r18's 3-buffer form) but: all rotation is &1 (r11: %3 costs VALU+VGPR),
// LDS 67.5 -> 50 KB. Sync structure (one true __syncthreads per tile,
// Ps double-buffer; empirical law r2/r7/r9) UNCHANGED.
// Q [2048][1024] bf16 (pre-scaled 0.125*log2e), Kmat [2048 kv][1024], Vt [1024 d][2048 kv]
__global__ __launch_bounds__(256) void attn_kernel(
    const bfu* __restrict__ Q, const bfu* __restrict__ Kmat,
    const bfu* __restrict__ Vt, bfu* __restrict__ O) {
  __shared__ alignas(16) bfu Ks[2][8][64][8];   // [buf][dgroup][kv][8]
  __shared__ alignas(16) bfu Vs[2][8][64][8];   // [buf][kvgroup8][d][8]
  __shared__ alignas(16) bfu Ps[2][64][72];     // double-buffered P
  const int tid = threadIdx.x, wave = tid >> 6, lane = tid & 63;
  const int g = lane >> 4, c = lane & 15;
  const int bid = blockIdx.x;
  const int xcd = bid & 7, slot = bid >> 3;
  const int h = xcd + 8 * (slot >> 5);          // head-major XCD swizzle [r18-proven]
  const int qblk = (slot & 31) * 64;
  const int col0 = h * 64;

  short8 qf[4][2];
#pragma unroll
  for (int qt = 0; qt < 4; ++qt) {
    qf[qt][0] = *(const short8*)&Q[(size_t)(qblk + qt * 16 + c) * 1024 + col0 + g * 8];
    qf[qt][1] = *(const short8*)&Q[(size_t)(qblk + qt * 16 + c) * 1024 + col0 + 32 + g * 8];
  }

  short8 ones;
#pragma unroll
  for (int e = 0; e < 8; ++e) ones[e] = (short)0x3F80;  // bf16 1.0

  f32x4 o_acc[4] = {};
  f32x4 lacc = {};

  auto stage_k = [&](int buf, int kv0) {   // 2 gload16/wave -> 8 pieces = full K tile
#pragma unroll
    for (int u = 0; u < 2; ++u) {
      int idx = wave * 2 + u;
      gload16(&Kmat[(size_t)(kv0 + lane) * 1024 + col0 + idx * 8], &Ks[buf][idx][0][0]);
    }
  };
  auto stage_v = [&](int buf, int kv0) {   // 2 gload16/wave -> 8 pieces = full V tile
#pragma unroll
    for (int u = 0; u < 2; ++u) {
      int idx = wave * 2 + u;
      gload16(&Vt[(size_t)(col0 + lane) * 2048 + kv0 + idx * 8], &Vs[buf][idx][0][0]);
    }
  };

  // QK-split: wave w computes S[all 64 q][kv chunk 16w..16w+15] -> Ps[pb]
  auto qk_exp = [&](int bQ, int pb) {
    short8 kf0 = *(const short8*)&Ks[bQ][g][wave * 16 + c][0];
    short8 kf1 = *(const short8*)&Ks[bQ][4 + g][wave * 16 + c][0];
    f32x4 s[4] = {};
    __builtin_amdgcn_s_setprio(1);
#pragma unroll
    for (int qt = 0; qt < 4; ++qt) {
      s[qt] = __builtin_amdgcn_mfma_f32_16x16x32_bf16(qf[qt][0], kf0, s[qt], 0, 0, 0);
      s[qt] = __builtin_amdgcn_mfma_f32_16x16x32_bf16(qf[qt][1], kf1, s[qt], 0, 0, 0);
    }
    __builtin_amdgcn_s_setprio(0);
    // P = 2^S via raw v_exp_f32 (log2e folded into Q) -- exactly exp(S_true)
#pragma unroll
    for (int qt = 0; qt < 4; ++qt)
#pragma unroll
      for (int j = 0; j < 4; ++j)
        Ps[pb][qt * 16 + g * 4 + j][wave * 16 + c] =
            f2bf(__builtin_amdgcn_exp2f(s[qt][j]));
  };

  // PV: wave w owns q-subtile w [proven indexing]
  auto pv = [&](int pb, int vb) {
    __builtin_amdgcn_s_setprio(1);
#pragma unroll
    for (int kc = 0; kc < 2; ++kc) {
      short8 pf = *(const short8*)&Ps[pb][wave * 16 + c][kc * 32 + g * 8];
      lacc = __builtin_amdgcn_mfma_f32_16x16x32_bf16(pf, ones, lacc, 0, 0, 0);
#pragma unroll
      for (int fd = 0; fd < 4; ++fd) {
        short8 vf = *(const short8*)&Vs[vb][kc * 4 + g][fd * 16 + c][0];
        o_acc[fd] = __builtin_amdgcn_mfma_f32_16x16x32_bf16(pf, vf, o_acc[fd], 0, 0, 0);
      }
    }
    __builtin_amdgcn_s_setprio(0);
  };

  stage_k(0, 0);
  __syncthreads();                       // drains K(0) + qf loads
  for (int t = 0; t < 32; ++t) {
    if (t < 31) stage_k((t + 1) & 1, (t + 1) * 64);
    stage_v(t & 1, t * 64);
    qk_exp(t & 1, t & 1);
    if (t > 0) pv((t - 1) & 1, (t - 1) & 1);   // exp VALU overlaps PV MFMA
    __syncthreads();                            // single barrier: Ps handoff + drains
  }
  pv(1, 1);                              // PV(31): Ps[31&1], Vs[31&1]

  const int q0 = qblk + wave * 16;
#pragma unroll
  for (int fd = 0; fd < 4; ++fd)
#pragma unroll
    for (int j = 0; j < 4; ++j) {
      float v = o_acc[fd][j] / lacc[j];
      O[(size_t)(q0 + g * 4 + j) * 1024 + col0 + fd * 16 + c] = f2bf(v);
    }
}

extern "C" void kernel_launch(void* const* d_in, const int* in_sizes, int n_in,
                              void* d_out, int out_size, void* d_ws, size_t ws_size,
                              hipStream_t stream) {
  const float* x   = (const float*)d_in[0];
  const float* ctx = (const float*)d_in[1];
  const float* Wq  = (const float*)d_in[2];
  const float* Wk  = (const float*)d_in[3];
  const float* Wv  = (const float*)d_in[4];
  const float* Wo  = (const float*)d_in[5];
  float* out = (float*)d_out;

  // ws: 10.25M bf16 elems (ws_size ~268MB per r18 fill trace -- ample).
  bfu* ws   = (bfu*)d_ws;
  bfu* xb   = ws;                        // 2M    (reused as attn-out)
  bfu* WTk  = xb + 2048 * 1024;          // 0.75M
  bfu* WTv  = WTk + 1024 * 768;          // 0.75M
  bfu* WTo  = WTv + 1024 * 768;          // 1M
  bfu* Qb   = WTo + 1024 * 1024;         // 2M
  bfu* Kb   = Qb + 2048 * 1024;          // 2M
  bfu* Vtb  = Kb + 2048 * 1024;          // 2M
  // d_out (8 MB f32) doubles as scratch for WTq + ctxb; both fully rewritten
  // each call before use, and gemmo overwrites all of d_out at the end.
  bfu* WTq  = (bfu*)d_out;               // 1M
  bfu* ctxb = WTq + 1024 * 1024;         // 1.5M  (total 5 MB <= 8 MB)

  dim3 blk(256);
  prep_kernel<<<5376, blk, 0, stream>>>(x, ctx, Wq, Wk, Wv, Wo, xb, ctxb, WTq, WTk, WTv, WTo);
  gemm3_kernel<<<384, blk, 0, stream>>>(xb, WTq, Qb, ctxb, WTk, Kb, WTv, Vtb);
  attn_kernel<<<512, blk, 0, stream>>>(Qb, Kb, Vtb, xb);
  gemmo_kernel<<<256, blk, 0, stream>>>(xb, WTo, out);
}

// Round 20
// 110.226 us; speedup vs baseline: 1.0898x; 1.0898x over previous
//
#include <hip/hip_runtime.h>
#include <hip/hip_bf16.h>
#include <stdint.h>

typedef unsigned short bfu;
typedef __attribute__((ext_vector_type(8))) short short8;
typedef __attribute__((ext_vector_type(4))) float f32x4;

#define LOG2E 1.4426950408889634f

__device__ __forceinline__ bfu f2bf(float f) {
  union { float f; uint32_t u; } v; v.f = f;
  uint32_t r = (v.u + 0x7fffu + ((v.u >> 16) & 1u)) >> 16;
  return (bfu)r;
}

__device__ __forceinline__ void gload16(const void* g, void* l) {
  __builtin_amdgcn_global_load_lds((const __attribute__((address_space(1))) void*)g,
                                   (__attribute__((address_space(3))) void*)l, 16, 0, 0);
}

// ---------------- prep: conv x, conv ctx, transpose 4 weights -- one launch [proven] ----------------
__device__ __forceinline__ void conv_body(const float* __restrict__ in, bfu* __restrict__ out,
                                          int i) {
  const float4* p = (const float4*)in + (size_t)i * 2;
  float4 a = p[0], b = p[1];
  union { bfu h[8]; uint4 v; } o;
  o.h[0] = f2bf(a.x); o.h[1] = f2bf(a.y); o.h[2] = f2bf(a.z); o.h[3] = f2bf(a.w);
  o.h[4] = f2bf(b.x); o.h[5] = f2bf(b.y); o.h[6] = f2bf(b.z); o.h[7] = f2bf(b.w);
  ((uint4*)out)[i] = o.v;
}

__device__ __forceinline__ void trans_body(const float* __restrict__ W, bfu* __restrict__ WT,
                                           int Kd, int n0, int k0) {
  __shared__ float tile[32][33];
  const int tx = threadIdx.x & 31, ty = threadIdx.x >> 5;
#pragma unroll
  for (int i = 0; i < 32; i += 8)
    tile[ty + i][tx] = W[(size_t)(k0 + ty + i) * 1024 + n0 + tx];
  __syncthreads();
#pragma unroll
  for (int i = 0; i < 32; i += 8)
    WT[(size_t)(n0 + ty + i) * Kd + k0 + tx] = f2bf(tile[tx][ty + i]);
}

__global__ __launch_bounds__(256) void prep_kernel(
    const float* __restrict__ x, const float* __restrict__ ctx,
    const float* __restrict__ Wq, const float* __restrict__ Wk,
    const float* __restrict__ Wv, const float* __restrict__ Wo,
    bfu* xb, bfu* ctxb, bfu* WTq, bfu* WTk, bfu* WTv, bfu* WTo) {
  int b = blockIdx.x;
  if (b < 1024)       conv_body(x, xb, b * 256 + threadIdx.x);
  else if (b < 1792)  conv_body(ctx, ctxb, (b - 1024) * 256 + threadIdx.x);
  else if (b < 2816) { b -= 1792; trans_body(Wq, WTq, 1024, (b & 31) * 32, (b >> 5) * 32); }
  else if (b < 3584) { b -= 2816; trans_body(Wk, WTk, 768, (b & 31) * 32, (b >> 5) * 32); }
  else if (b < 4352) { b -= 3584; trans_body(Wv, WTv, 768, (b & 31) * 32, (b >> 5) * 32); }
  else               { b -= 4352; trans_body(Wo, WTo, 1024, (b & 31) * 32, (b >> 5) * 32); }
}

// ---------------- 128x128 GEMM body (r8/r17-PROVEN), BK=32, async dbuf ----------------
typedef bfu Tile128[2][4][128][8];

__device__ __forceinline__ void gemm128_body(Tile128& As2, Tile128& Bs2,
    const bfu* __restrict__ A, const bfu* __restrict__ BT,
    bfu* __restrict__ Cb, int N, int K, float scale, int m0, int n0) {
  const int tid = threadIdx.x, lane = tid & 63, wave = tid >> 6;
  const int g = lane >> 4, c = lane & 15;
  const int wm = (wave >> 1) * 64, wn = (wave & 1) * 64;
  const int nt = K / 32;

  auto stage = [&](int buf, int kt) {
#pragma unroll
    for (int u = 0; u < 4; ++u) {
      int idx = wave * 4 + u;
      if (idx < 8) {
        int kg = idx & 3, rb = idx >> 2;
        gload16(&A[(size_t)(m0 + rb * 64 + lane) * K + kt + kg * 8], &As2[buf][kg][rb * 64][0]);
      } else {
        int kg = (idx - 8) & 3, rb = (idx - 8) >> 2;
        gload16(&BT[(size_t)(n0 + rb * 64 + lane) * K + kt + kg * 8], &Bs2[buf][kg][rb * 64][0]);
      }
    }
  };

  f32x4 acc[4][4] = {};
  stage(0, 0);
  for (int t = 0; t < nt; ++t) {
    __syncthreads();
    if (t + 1 < nt) stage((t + 1) & 1, (t + 1) * 32);
    const int b = t & 1;
    short8 af[4], bfr[4];
#pragma unroll
    for (int i = 0; i < 4; ++i) {
      af[i]  = *(const short8*)&As2[b][g][wm + i * 16 + c][0];
      bfr[i] = *(const short8*)&Bs2[b][g][wn + i * 16 + c][0];
    }
#pragma unroll
    for (int i = 0; i < 4; ++i)
#pragma unroll
      for (int j = 0; j < 4; ++j)
        acc[i][j] = __builtin_amdgcn_mfma_f32_16x16x32_bf16(af[i], bfr[j], acc[i][j], 0, 0, 0);
  }
#pragma unroll
  for (int i = 0; i < 4; ++i)
#pragma unroll
    for (int j = 0; j < 4; ++j) {
      int row = m0 + wm + i * 16 + g * 4;
      int col = n0 + wn + j * 16 + c;
#pragma unroll
      for (int r = 0; r < 4; ++r)
        Cb[(size_t)(row + r) * N + col] = f2bf(acc[i][j][r] * scale);
    }
}

// fused Q/K/V projections at 128x128: 384 blocks  [r17-proven]
__global__ __launch_bounds__(256) void gemm3_kernel(
    const bfu* __restrict__ xb, const bfu* __restrict__ WTq, bfu* __restrict__ Qb,
    const bfu* __restrict__ ctxb, const bfu* __restrict__ WTk, bfu* __restrict__ Kb,
    const bfu* __restrict__ WTv, bfu* __restrict__ Vtb) {
  __shared__ alignas(16) bfu As2[2][4][128][8];
  __shared__ alignas(16) bfu Bs2[2][4][128][8];
  int bid = blockIdx.x;
  if (bid < 128)
    gemm128_body(As2, Bs2, xb, WTq, Qb, 1024, 1024, 0.125f * LOG2E, (bid >> 3) * 128, (bid & 7) * 128);
  else if (bid < 256) {
    int r = bid - 128;
    gemm128_body(As2, Bs2, ctxb, WTk, Kb, 1024, 768, 1.0f, (r >> 3) * 128, (r & 7) * 128);
  } else {  // V^T = Wv^T @ ctx^T : A = WTv (1024x768), BT = ctxb (2048x768)
    int r = bid - 256;
    gemm128_body(As2, Bs2, WTv, ctxb, Vtb, 2048, 768, 1.0f, (r >> 4) * 128, (r & 15) * 128);
  }
}

// ---------------- 128x64 GEMM body [proven verbatim] -- output projection ----------------
typedef bfu AsArr[2][4][128][8];
typedef bfu BsArr[2][4][64][8];

__device__ __forceinline__ void gemm_body(AsArr& As2, BsArr& Bs2,
    const bfu* __restrict__ A, const bfu* __restrict__ BT,
    bfu* __restrict__ Cb, float* __restrict__ Cf,
    int N, int K, float scale, int m0, int n0) {
  const int tid = threadIdx.x, lane = tid & 63, wave = tid >> 6;
  const int g = lane >> 4, c = lane & 15;
  const int wm = wave * 32;
  const int nt = K / 32;

  auto stage = [&](int buf, int kt) {
#pragma unroll
    for (int u = 0; u < 3; ++u) {
      int idx = wave * 3 + u;
      if (idx < 8) {
        int g2 = idx & 3, rb = idx >> 2;
        gload16(&A[(size_t)(m0 + rb * 64 + lane) * K + kt + g2 * 8], &As2[buf][g2][rb * 64][0]);
      } else {
        int g2 = idx - 8;
        gload16(&BT[(size_t)(n0 + lane) * K + kt + g2 * 8], &Bs2[buf][g2][0][0]);
      }
    }
  };

  f32x4 acc[2][4] = {};
  stage(0, 0);
  for (int t = 0; t < nt; ++t) {
    __syncthreads();
    if (t + 1 < nt) stage((t + 1) & 1, (t + 1) * 32);
    const int b = t & 1;
    short8 af[2], bfr[4];
#pragma unroll
    for (int i = 0; i < 2; ++i) af[i] = *(const short8*)&As2[b][g][wm + i * 16 + c][0];
#pragma unroll
    for (int j = 0; j < 4; ++j) bfr[j] = *(const short8*)&Bs2[b][g][j * 16 + c][0];
#pragma unroll
    for (int i = 0; i < 2; ++i)
#pragma unroll
      for (int j = 0; j < 4; ++j)
        acc[i][j] = __builtin_amdgcn_mfma_f32_16x16x32_bf16(af[i], bfr[j], acc[i][j], 0, 0, 0);
  }
#pragma unroll
  for (int i = 0; i < 2; ++i)
#pragma unroll
    for (int j = 0; j < 4; ++j) {
      int row = m0 + wm + i * 16 + g * 4;
      int col = n0 + j * 16 + c;
#pragma unroll
      for (int r = 0; r < 4; ++r) {
        float v = acc[i][j][r] * scale;
        if (Cb) Cb[(size_t)(row + r) * N + col] = f2bf(v);
        else    Cf[(size_t)(row + r) * N + col] = v;
      }
    }
}

// output projection: f32 out, 256 blocks  [proven]
__global__ __launch_bounds__(256) void gemmo_kernel(const bfu* __restrict__ AO,
                                                    const bfu* __restrict__ WTo,
                                                    float* __restrict__ out) {
  __shared__ alignas(16) bfu As2[2][4][128][8];
  __shared__ alignas(16) bfu Bs2[2][4][64][8];
  int bid = blockIdx.x;
  gemm_body(As2, Bs2, AO, WTo, nullptr, out, 1024, 1024, 1.0f, (bid >> 4) * 128, (bid & 15) * 64);
}

// ---------------- flash attention [r18 CHAMPION, verbatim: 45.0 us] ----------------
// %3 triple-buffer, joint K+V stage, one barrier/tile, raw v_exp_f32,
// head-major XCD swizzle. r19's staggered-&1 variant regressed (52.5) -- reverted.
// Q [2048][1024] bf16 (pre-scaled 0.125*log2e), Kmat [2048 kv][1024], Vt [1024 d][2048 kv]
__global__ __launch_bounds__(256) void attn_kernel(
    const bfu* __restrict__ Q, const bfu* __restrict__ Kmat,
    const bfu* __restrict__ Vt, bfu* __restrict__ O) {
  __shared__ alignas(16) bfu Ks[3][8][64][8];   // [buf][dgroup][kv][8]
  __shared__ alignas(16) bfu Vs[3][8][64][8];   // [buf][kvgroup8][d][8]
  __shared__ alignas(16) bfu Ps[2][64][72];     // double-buffered P
  const int tid = threadIdx.x, wave = tid >> 6, lane = tid & 63;
  const int g = lane >> 4, c = lane & 15;
  const int bid = blockIdx.x;
  const int xcd = bid & 7, slot = bid >> 3;
  const int h = xcd + 8 * (slot >> 5);          // bijective: 2 heads/XCD
  const int qblk = (slot & 31) * 64;
  const int col0 = h * 64;

  short8 qf[4][2];
#pragma unroll
  for (int qt = 0; qt < 4; ++qt) {
    qf[qt][0] = *(const short8*)&Q[(size_t)(qblk + qt * 16 + c) * 1024 + col0 + g * 8];
    qf[qt][1] = *(const short8*)&Q[(size_t)(qblk + qt * 16 + c) * 1024 + col0 + 32 + g * 8];
  }

  short8 ones;
#pragma unroll
  for (int e = 0; e < 8; ++e) ones[e] = (short)0x3F80;  // bf16 1.0

  f32x4 o_acc[4] = {};
  f32x4 lacc = {};

  auto stage = [&](int buf, int kv0) {   // 4 gload16/wave [proven]
#pragma unroll
    for (int u = 0; u < 4; ++u) {
      int idx = wave * 4 + u;
      if (idx < 8)
        gload16(&Kmat[(size_t)(kv0 + lane) * 1024 + col0 + idx * 8], &Ks[buf][idx][0][0]);
      else
        gload16(&Vt[(size_t)(col0 + lane) * 2048 + kv0 + (idx - 8) * 8], &Vs[buf][idx - 8][0][0]);
    }
  };

  // QK-split: wave w computes S[all 64 q][kv chunk 16w..16w+15] -> Ps[pb]
  auto qk_exp = [&](int bQ, int pb) {
    short8 kf0 = *(const short8*)&Ks[bQ][g][wave * 16 + c][0];
    short8 kf1 = *(const short8*)&Ks[bQ][4 + g][wave * 16 + c][0];
    f32x4 s[4] = {};
    __builtin_amdgcn_s_setprio(1);
#pragma unroll
    for (int qt = 0; qt < 4; ++qt) {
      s[qt] = __builtin_amdgcn_mfma_f32_16x16x32_bf16(qf[qt][0], kf0, s[qt], 0, 0, 0);
      s[qt] = __builtin_amdgcn_mfma_f32_16x16x32_bf16(qf[qt][1], kf1, s[qt], 0, 0, 0);
    }
    __builtin_amdgcn_s_setprio(0);
    // P = 2^S via raw v_exp_f32 (log2e folded into Q) -- exactly exp(S_true)
#pragma unroll
    for (int qt = 0; qt < 4; ++qt)
#pragma unroll
      for (int j = 0; j < 4; ++j)
        Ps[pb][qt * 16 + g * 4 + j][wave * 16 + c] =
            f2bf(__builtin_amdgcn_exp2f(s[qt][j]));
  };

  // PV: wave w owns q-subtile w [proven indexing]
  auto pv = [&](int pb, int vb) {
    __builtin_amdgcn_s_setprio(1);
#pragma unroll
    for (int kc = 0; kc < 2; ++kc) {
      short8 pf = *(const short8*)&Ps[pb][wave * 16 + c][kc * 32 + g * 8];
      lacc = __builtin_amdgcn_mfma_f32_16x16x32_bf16(pf, ones, lacc, 0, 0, 0);
#pragma unroll
      for (int fd = 0; fd < 4; ++fd) {
        short8 vf = *(const short8*)&Vs[vb][kc * 4 + g][fd * 16 + c][0];
        o_acc[fd] = __builtin_amdgcn_mfma_f32_16x16x32_bf16(pf, vf, o_acc[fd], 0, 0, 0);
      }
    }
    __builtin_amdgcn_s_setprio(0);
  };

  stage(0, 0);
  __syncthreads();           // drains stage(0) + qf loads
  stage(1, 64);
  qk_exp(0, 0);
  __syncthreads();
  for (int t = 1; t < 32; ++t) {
    stage((t + 1) % 3, ((t + 1) & 31) * 64);   // t=31 wraps: redundant, never read
    qk_exp(t % 3, t & 1);
    pv((t - 1) & 1, (t - 1) % 3);              // exp VALU overlaps PV MFMA
    __syncthreads();                           // single barrier: Ps handoff + buffers
  }
  pv(1, 1);                                    // PV(31): Ps[31&1], Vs[31%3]

  const int q0 = qblk + wave * 16;
#pragma unroll
  for (int fd = 0; fd < 4; ++fd)
#pragma unroll
    for (int j = 0; j < 4; ++j) {
      float v = o_acc[fd][j] / lacc[j];
      O[(size_t)(q0 + g * 4 + j) * 1024 + col0 + fd * 16 + c] = f2bf(v);
    }
}

extern "C" void kernel_launch(void* const* d_in, const int* in_sizes, int n_in,
                              void* d_out, int out_size, void* d_ws, size_t ws_size,
                              hipStream_t stream) {
  const float* x   = (const float*)d_in[0];
  const float* ctx = (const float*)d_in[1];
  const float* Wq  = (const float*)d_in[2];
  const float* Wk  = (const float*)d_in[3];
  const float* Wv  = (const float*)d_in[4];
  const float* Wo  = (const float*)d_in[5];
  float* out = (float*)d_out;

  // ws: 10.25M bf16 elems (ws_size ~268MB per r18 fill trace -- ample).
  bfu* ws   = (bfu*)d_ws;
  bfu* xb   = ws;                        // 2M    (reused as attn-out)
  bfu* WTk  = xb + 2048 * 1024;          // 0.75M
  bfu* WTv  = WTk + 1024 * 768;          // 0.75M
  bfu* WTo  = WTv + 1024 * 768;          // 1M
  bfu* Qb   = WTo + 1024 * 1024;         // 2M
  bfu* Kb   = Qb + 2048 * 1024;          // 2M
  bfu* Vtb  = Kb + 2048 * 1024;          // 2M
  // d_out (8 MB f32) doubles as scratch for WTq + ctxb; both fully rewritten
  // each call before use, and gemmo overwrites all of d_out at the end.
  bfu* WTq  = (bfu*)d_out;               // 1M
  bfu* ctxb = WTq + 1024 * 1024;         // 1.5M  (total 5 MB <= 8 MB)

  dim3 blk(256);
  prep_kernel<<<5376, blk, 0, stream>>>(x, ctx, Wq, Wk, Wv, Wo, xb, ctxb, WTq, WTk, WTv, WTo);
  gemm3_kernel<<<384, blk, 0, stream>>>(xb, WTq, Qb, ctxb, WTk, Kb, WTv, Vtb);
  attn_kernel<<<512, blk, 0, stream>>>(Qb, Kb, Vtb, xb);
  gemmo_kernel<<<256, blk, 0, stream>>>(xb, WTo, out);
}

// Round 21
// 106.841 us; speedup vs baseline: 1.1243x; 1.0317x over previous
//
#include <hip/hip_runtime.h>
#include <hip/hip_bf16.h>
#include <stdint.h>

typedef unsigned short bfu;
typedef __attribute__((ext_vector_type(8))) short short8;
typedef __attribute__((ext_vector_type(4))) float f32x4;

#define LOG2E 1.4426950408889634f

__device__ __forceinline__ bfu f2bf(float f) {
  union { float f; uint32_t u; } v; v.f = f;
  uint32_t r = (v.u + 0x7fffu + ((v.u >> 16) & 1u)) >> 16;
  return (bfu)r;
}

__device__ __forceinline__ void gload16(const void* g, void* l) {
  __builtin_amdgcn_global_load_lds((const __attribute__((address_space(1))) void*)g,
                                   (__attribute__((address_space(3))) void*)l, 16, 0, 0);
}

// ---------------- prep: conv x, conv ctx, transpose 4 weights -- one launch [proven] ----------------
__device__ __forceinline__ void conv_body(const float* __restrict__ in, bfu* __restrict__ out,
                                          int i) {
  const float4* p = (const float4*)in + (size_t)i * 2;
  float4 a = p[0], b = p[1];
  union { bfu h[8]; uint4 v; } o;
  o.h[0] = f2bf(a.x); o.h[1] = f2bf(a.y); o.h[2] = f2bf(a.z); o.h[3] = f2bf(a.w);
  o.h[4] = f2bf(b.x); o.h[5] = f2bf(b.y); o.h[6] = f2bf(b.z); o.h[7] = f2bf(b.w);
  ((uint4*)out)[i] = o.v;
}

__device__ __forceinline__ void trans_body(const float* __restrict__ W, bfu* __restrict__ WT,
                                           int Kd, int n0, int k0) {
  __shared__ float tile[32][33];
  const int tx = threadIdx.x & 31, ty = threadIdx.x >> 5;
#pragma unroll
  for (int i = 0; i < 32; i += 8)
    tile[ty + i][tx] = W[(size_t)(k0 + ty + i) * 1024 + n0 + tx];
  __syncthreads();
#pragma unroll
  for (int i = 0; i < 32; i += 8)
    WT[(size_t)(n0 + ty + i) * Kd + k0 + tx] = f2bf(tile[tx][ty + i]);
}

__global__ __launch_bounds__(256) void prep_kernel(
    const float* __restrict__ x, const float* __restrict__ ctx,
    const float* __restrict__ Wq, const float* __restrict__ Wk,
    const float* __restrict__ Wv, const float* __restrict__ Wo,
    bfu* xb, bfu* ctxb, bfu* WTq, bfu* WTk, bfu* WTv, bfu* WTo) {
  int b = blockIdx.x;
  if (b < 1024)       conv_body(x, xb, b * 256 + threadIdx.x);
  else if (b < 1792)  conv_body(ctx, ctxb, (b - 1024) * 256 + threadIdx.x);
  else if (b < 2816) { b -= 1792; trans_body(Wq, WTq, 1024, (b & 31) * 32, (b >> 5) * 32); }
  else if (b < 3584) { b -= 2816; trans_body(Wk, WTk, 768, (b & 31) * 32, (b >> 5) * 32); }
  else if (b < 4352) { b -= 3584; trans_body(Wv, WTv, 768, (b & 31) * 32, (b >> 5) * 32); }
  else               { b -= 4352; trans_body(Wo, WTo, 1024, (b & 31) * 32, (b >> 5) * 32); }
}

// ---------------- 128x128 GEMM body (r8/r17-PROVEN), BK=32, async dbuf ----------------
typedef bfu Tile128[2][4][128][8];

__device__ __forceinline__ void gemm128_body(Tile128& As2, Tile128& Bs2,
    const bfu* __restrict__ A, const bfu* __restrict__ BT,
    bfu* __restrict__ Cb, int N, int K, float scale, int m0, int n0) {
  const int tid = threadIdx.x, lane = tid & 63, wave = tid >> 6;
  const int g = lane >> 4, c = lane & 15;
  const int wm = (wave >> 1) * 64, wn = (wave & 1) * 64;
  const int nt = K / 32;

  auto stage = [&](int buf, int kt) {
#pragma unroll
    for (int u = 0; u < 4; ++u) {
      int idx = wave * 4 + u;
      if (idx < 8) {
        int kg = idx & 3, rb = idx >> 2;
        gload16(&A[(size_t)(m0 + rb * 64 + lane) * K + kt + kg * 8], &As2[buf][kg][rb * 64][0]);
      } else {
        int kg = (idx - 8) & 3, rb = (idx - 8) >> 2;
        gload16(&BT[(size_t)(n0 + rb * 64 + lane) * K + kt + kg * 8], &Bs2[buf][kg][rb * 64][0]);
      }
    }
  };

  f32x4 acc[4][4] = {};
  stage(0, 0);
  for (int t = 0; t < nt; ++t) {
    __syncthreads();
    if (t + 1 < nt) stage((t + 1) & 1, (t + 1) * 32);
    const int b = t & 1;
    short8 af[4], bfr[4];
#pragma unroll
    for (int i = 0; i < 4; ++i) {
      af[i]  = *(const short8*)&As2[b][g][wm + i * 16 + c][0];
      bfr[i] = *(const short8*)&Bs2[b][g][wn + i * 16 + c][0];
    }
#pragma unroll
    for (int i = 0; i < 4; ++i)
#pragma unroll
      for (int j = 0; j < 4; ++j)
        acc[i][j] = __builtin_amdgcn_mfma_f32_16x16x32_bf16(af[i], bfr[j], acc[i][j], 0, 0, 0);
  }
#pragma unroll
  for (int i = 0; i < 4; ++i)
#pragma unroll
    for (int j = 0; j < 4; ++j) {
      int row = m0 + wm + i * 16 + g * 4;
      int col = n0 + wn + j * 16 + c;
#pragma unroll
      for (int r = 0; r < 4; ++r)
        Cb[(size_t)(row + r) * N + col] = f2bf(acc[i][j][r] * scale);
    }
}

// ---------------- 128x64 GEMM body [proven verbatim] ----------------
typedef bfu AsArr[2][4][128][8];
typedef bfu BsArr[2][4][64][8];

__device__ __forceinline__ void gemm_body(AsArr& As2, BsArr& Bs2,
    const bfu* __restrict__ A, const bfu* __restrict__ BT,
    bfu* __restrict__ Cb, float* __restrict__ Cf,
    int N, int K, float scale, int m0, int n0) {
  const int tid = threadIdx.x, lane = tid & 63, wave = tid >> 6;
  const int g = lane >> 4, c = lane & 15;
  const int wm = wave * 32;
  const int nt = K / 32;

  auto stage = [&](int buf, int kt) {
#pragma unroll
    for (int u = 0; u < 3; ++u) {
      int idx = wave * 3 + u;
      if (idx < 8) {
        int g2 = idx & 3, rb = idx >> 2;
        gload16(&A[(size_t)(m0 + rb * 64 + lane) * K + kt + g2 * 8], &As2[buf][g2][rb * 64][0]);
      } else {
        int g2 = idx - 8;
        gload16(&BT[(size_t)(n0 + lane) * K + kt + g2 * 8], &Bs2[buf][g2][0][0]);
      }
    }
  };

  f32x4 acc[2][4] = {};
  stage(0, 0);
  for (int t = 0; t < nt; ++t) {
    __syncthreads();
    if (t + 1 < nt) stage((t + 1) & 1, (t + 1) * 32);
    const int b = t & 1;
    short8 af[2], bfr[4];
#pragma unroll
    for (int i = 0; i < 2; ++i) af[i] = *(const short8*)&As2[b][g][wm + i * 16 + c][0];
#pragma unroll
    for (int j = 0; j < 4; ++j) bfr[j] = *(const short8*)&Bs2[b][g][j * 16 + c][0];
#pragma unroll
    for (int i = 0; i < 2; ++i)
#pragma unroll
      for (int j = 0; j < 4; ++j)
        acc[i][j] = __builtin_amdgcn_mfma_f32_16x16x32_bf16(af[i], bfr[j], acc[i][j], 0, 0, 0);
  }
#pragma unroll
  for (int i = 0; i < 2; ++i)
#pragma unroll
    for (int j = 0; j < 4; ++j) {
      int row = m0 + wm + i * 16 + g * 4;
      int col = n0 + j * 16 + c;
#pragma unroll
      for (int r = 0; r < 4; ++r) {
        float v = acc[i][j][r] * scale;
        if (Cb) Cb[(size_t)(row + r) * N + col] = f2bf(v);
        else    Cf[(size_t)(row + r) * N + col] = v;
      }
    }
}

// fused Q/K/V projections, BALANCED 512 blocks = exactly 2/CU:
// Q (128 blocks @128x128) + K (128 @128x128) + V^T (256 @128x64, r10-proven form).
__global__ __launch_bounds__(256) void gemm3_kernel(
    const bfu* __restrict__ xb, const bfu* __restrict__ WTq, bfu* __restrict__ Qb,
    const bfu* __restrict__ ctxb, const bfu* __restrict__ WTk, bfu* __restrict__ Kb,
    const bfu* __restrict__ WTv, bfu* __restrict__ Vtb) {
  __shared__ alignas(16) bfu As2[2][4][128][8];
  __shared__ alignas(16) bfu Bs2[2][4][128][8];
  int bid = blockIdx.x;
  if (bid < 128)
    gemm128_body(As2, Bs2, xb, WTq, Qb, 1024, 1024, 0.125f * LOG2E, (bid >> 3) * 128, (bid & 7) * 128);
  else if (bid < 256) {
    int r = bid - 128;
    gemm128_body(As2, Bs2, ctxb, WTk, Kb, 1024, 768, 1.0f, (r >> 3) * 128, (r & 7) * 128);
  } else {  // V^T = Wv^T @ ctx^T at 128x64: A = WTv (1024x768), BT = ctxb (2048x768)
    int r = bid - 256;                   // 0..255 -> (1024/128) x (2048/64)
    gemm_body(*(AsArr*)As2, *(BsArr*)Bs2, WTv, ctxb, Vtb, nullptr,
              2048, 768, 1.0f, (r >> 5) * 128, (r & 31) * 64);
  }
}

// output projection: f32 out, 256 blocks  [proven]
__global__ __launch_bounds__(256) void gemmo_kernel(const bfu* __restrict__ AO,
                                                    const bfu* __restrict__ WTo,
                                                    float* __restrict__ out) {
  __shared__ alignas(16) bfu As2[2][4][128][8];
  __shared__ alignas(16) bfu Bs2[2][4][64][8];
  int bid = blockIdx.x;
  gemm_body(As2, Bs2, AO, WTo, nullptr, out, 1024, 1024, 1.0f, (bid >> 4) * 128, (bid & 15) * 64);
}

// ---------------- flash attention [r18 CHAMPION, verbatim: 45.0 us] ----------------
// %3 triple-buffer, joint K+V stage, one barrier/tile, raw v_exp_f32,
// head-major XCD swizzle.
// Q [2048][1024] bf16 (pre-scaled 0.125*log2e), Kmat [2048 kv][1024], Vt [1024 d][2048 kv]
__global__ __launch_bounds__(256) void attn_kernel(
    const bfu* __restrict__ Q, const bfu* __restrict__ Kmat,
    const bfu* __restrict__ Vt, bfu* __restrict__ O) {
  __shared__ alignas(16) bfu Ks[3][8][64][8];   // [buf][dgroup][kv][8]
  __shared__ alignas(16) bfu Vs[3][8][64][8];   // [buf][kvgroup8][d][8]
  __shared__ alignas(16) bfu Ps[2][64][72];     // double-buffered P
  const int tid = threadIdx.x, wave = tid >> 6, lane = tid & 63;
  const int g = lane >> 4, c = lane & 15;
  const int bid = blockIdx.x;
  const int xcd = bid & 7, slot = bid >> 3;
  const int h = xcd + 8 * (slot >> 5);          // bijective: 2 heads/XCD
  const int qblk = (slot & 31) * 64;
  const int col0 = h * 64;

  short8 qf[4][2];
#pragma unroll
  for (int qt = 0; qt < 4; ++qt) {
    qf[qt][0] = *(const short8*)&Q[(size_t)(qblk + qt * 16 + c) * 1024 + col0 + g * 8];
    qf[qt][1] = *(const short8*)&Q[(size_t)(qblk + qt * 16 + c) * 1024 + col0 + 32 + g * 8];
  }

  short8 ones;
#pragma unroll
  for (int e = 0; e < 8; ++e) ones[e] = (short)0x3F80;  // bf16 1.0

  f32x4 o_acc[4] = {};
  f32x4 lacc = {};

  auto stage = [&](int buf, int kv0) {   // 4 gload16/wave [proven]
#pragma unroll
    for (int u = 0; u < 4; ++u) {
      int idx = wave * 4 + u;
      if (idx < 8)
        gload16(&Kmat[(size_t)(kv0 + lane) * 1024 + col0 + idx * 8], &Ks[buf][idx][0][0]);
      else
        gload16(&Vt[(size_t)(col0 + lane) * 2048 + kv0 + (idx - 8) * 8], &Vs[buf][idx - 8][0][0]);
    }
  };

  // QK-split: wave w computes S[all 64 q][kv chunk 16w..16w+15] -> Ps[pb]
  auto qk_exp = [&](int bQ, int pb) {
    short8 kf0 = *(const short8*)&Ks[bQ][g][wave * 16 + c][0];
    short8 kf1 = *(const short8*)&Ks[bQ][4 + g][wave * 16 + c][0];
    f32x4 s[4] = {};
    __builtin_amdgcn_s_setprio(1);
#pragma unroll
    for (int qt = 0; qt < 4; ++qt) {
      s[qt] = __builtin_amdgcn_mfma_f32_16x16x32_bf16(qf[qt][0], kf0, s[qt], 0, 0, 0);
      s[qt] = __builtin_amdgcn_mfma_f32_16x16x32_bf16(qf[qt][1], kf1, s[qt], 0, 0, 0);
    }
    __builtin_amdgcn_s_setprio(0);
    // P = 2^S via raw v_exp_f32 (log2e folded into Q) -- exactly exp(S_true)
#pragma unroll
    for (int qt = 0; qt < 4; ++qt)
#pragma unroll
      for (int j = 0; j < 4; ++j)
        Ps[pb][qt * 16 + g * 4 + j][wave * 16 + c] =
            f2bf(__builtin_amdgcn_exp2f(s[qt][j]));
  };

  // PV: wave w owns q-subtile w [proven indexing]
  auto pv = [&](int pb, int vb) {
    __builtin_amdgcn_s_setprio(1);
#pragma unroll
    for (int kc = 0; kc < 2; ++kc) {
      short8 pf = *(const short8*)&Ps[pb][wave * 16 + c][kc * 32 + g * 8];
      lacc = __builtin_amdgcn_mfma_f32_16x16x32_bf16(pf, ones, lacc, 0, 0, 0);
#pragma unroll
      for (int fd = 0; fd < 4; ++fd) {
        short8 vf = *(const short8*)&Vs[vb][kc * 4 + g][fd * 16 + c][0];
        o_acc[fd] = __builtin_amdgcn_mfma_f32_16x16x32_bf16(pf, vf, o_acc[fd], 0, 0, 0);
      }
    }
    __builtin_amdgcn_s_setprio(0);
  };

  stage(0, 0);
  __syncthreads();           // drains stage(0) + qf loads
  stage(1, 64);
  qk_exp(0, 0);
  __syncthreads();
  for (int t = 1; t < 32; ++t) {
    stage((t + 1) % 3, ((t + 1) & 31) * 64);   // t=31 wraps: redundant, never read
    qk_exp(t % 3, t & 1);
    pv((t - 1) & 1, (t - 1) % 3);              // exp VALU overlaps PV MFMA
    __syncthreads();                           // single barrier: Ps handoff + buffers
  }
  pv(1, 1);                                    // PV(31): Ps[31&1], Vs[31%3]

  const int q0 = qblk + wave * 16;
#pragma unroll
  for (int fd = 0; fd < 4; ++fd)
#pragma unroll
    for (int j = 0; j < 4; ++j) {
      float v = o_acc[fd][j] / lacc[j];
      O[(size_t)(q0 + g * 4 + j) * 1024 + col0 + fd * 16 + c] = f2bf(v);
    }
}

extern "C" void kernel_launch(void* const* d_in, const int* in_sizes, int n_in,
                              void* d_out, int out_size, void* d_ws, size_t ws_size,
                              hipStream_t stream) {
  const float* x   = (const float*)d_in[0];
  const float* ctx = (const float*)d_in[1];
  const float* Wq  = (const float*)d_in[2];
  const float* Wk  = (const float*)d_in[3];
  const float* Wv  = (const float*)d_in[4];
  const float* Wo  = (const float*)d_in[5];
  float* out = (float*)d_out;

  // ws: 10.25M bf16 elems (ws_size ~268MB per r18 fill trace -- ample).
  bfu* ws   = (bfu*)d_ws;
  bfu* xb   = ws;                        // 2M    (reused as attn-out)
  bfu* WTk  = xb + 2048 * 1024;          // 0.75M
  bfu* WTv  = WTk + 1024 * 768;          // 0.75M
  bfu* WTo  = WTv + 1024 * 768;          // 1M
  bfu* Qb   = WTo + 1024 * 1024;         // 2M
  bfu* Kb   = Qb + 2048 * 1024;          // 2M
  bfu* Vtb  = Kb + 2048 * 1024;          // 2M
  // d_out (8 MB f32) doubles as scratch for WTq + ctxb; both fully rewritten
  // each call before use, and gemmo overwrites all of d_out at the end.
  bfu* WTq  = (bfu*)d_out;               // 1M
  bfu* ctxb = WTq + 1024 * 1024;         // 1.5M  (total 5 MB <= 8 MB)

  dim3 blk(256);
  prep_kernel<<<5376, blk, 0, stream>>>(x, ctx, Wq, Wk, Wv, Wo, xb, ctxb, WTq, WTk, WTv, WTo);
  gemm3_kernel<<<512, blk, 0, stream>>>(xb, WTq, Qb, ctxb, WTk, Kb, WTv, Vtb);
  attn_kernel<<<512, blk, 0, stream>>>(Qb, Kb, Vtb, xb);
  gemmo_kernel<<<256, blk, 0, stream>>>(xb, WTo, out);
}

// Round 22
// 106.113 us; speedup vs baseline: 1.1320x; 1.0069x over previous
//
#include <hip/hip_runtime.h>
#include <hip/hip_bf16.h>
#include <stdint.h>

typedef unsigned short bfu;
typedef __attribute__((ext_vector_type(8))) short short8;
typedef __attribute__((ext_vector_type(4))) float f32x4;

#define LOG2E 1.4426950408889634f

__device__ __forceinline__ bfu f2bf(float f) {
  union { float f; uint32_t u; } v; v.f = f;
  uint32_t r = (v.u + 0x7fffu + ((v.u >> 16) & 1u)) >> 16;
  return (bfu)r;
}

__device__ __forceinline__ void gload16(const void* g, void* l) {
  __builtin_amdgcn_global_load_lds((const __attribute__((address_space(1))) void*)g,
                                   (__attribute__((address_space(3))) void*)l, 16, 0, 0);
}

// ---------------- prep: conv x, conv ctx, transpose 4 weights -- one launch [proven] ----------------
__device__ __forceinline__ void conv_body(const float* __restrict__ in, bfu* __restrict__ out,
                                          int i) {
  const float4* p = (const float4*)in + (size_t)i * 2;
  float4 a = p[0], b = p[1];
  union { bfu h[8]; uint4 v; } o;
  o.h[0] = f2bf(a.x); o.h[1] = f2bf(a.y); o.h[2] = f2bf(a.z); o.h[3] = f2bf(a.w);
  o.h[4] = f2bf(b.x); o.h[5] = f2bf(b.y); o.h[6] = f2bf(b.z); o.h[7] = f2bf(b.w);
  ((uint4*)out)[i] = o.v;
}

__device__ __forceinline__ void trans_body(const float* __restrict__ W, bfu* __restrict__ WT,
                                           int Kd, int n0, int k0) {
  __shared__ float tile[32][33];
  const int tx = threadIdx.x & 31, ty = threadIdx.x >> 5;
#pragma unroll
  for (int i = 0; i < 32; i += 8)
    tile[ty + i][tx] = W[(size_t)(k0 + ty + i) * 1024 + n0 + tx];
  __syncthreads();
#pragma unroll
  for (int i = 0; i < 32; i += 8)
    WT[(size_t)(n0 + ty + i) * Kd + k0 + tx] = f2bf(tile[tx][ty + i]);
}

__global__ __launch_bounds__(256) void prep_kernel(
    const float* __restrict__ x, const float* __restrict__ ctx,
    const float* __restrict__ Wq, const float* __restrict__ Wk,
    const float* __restrict__ Wv, const float* __restrict__ Wo,
    bfu* xb, bfu* ctxb, bfu* WTq, bfu* WTk, bfu* WTv, bfu* WTo) {
  int b = blockIdx.x;
  if (b < 1024)       conv_body(x, xb, b * 256 + threadIdx.x);
  else if (b < 1792)  conv_body(ctx, ctxb, (b - 1024) * 256 + threadIdx.x);
  else if (b < 2816) { b -= 1792; trans_body(Wq, WTq, 1024, (b & 31) * 32, (b >> 5) * 32); }
  else if (b < 3584) { b -= 2816; trans_body(Wk, WTk, 768, (b & 31) * 32, (b >> 5) * 32); }
  else if (b < 4352) { b -= 3584; trans_body(Wv, WTv, 768, (b & 31) * 32, (b >> 5) * 32); }
  else               { b -= 4352; trans_body(Wo, WTo, 1024, (b & 31) * 32, (b >> 5) * 32); }
}

// ---------------- 128x128 GEMM body (r8/r17-PROVEN), BK=32, async dbuf ----------------
typedef bfu Tile128[2][4][128][8];

__device__ __forceinline__ void gemm128_body(Tile128& As2, Tile128& Bs2,
    const bfu* __restrict__ A, const bfu* __restrict__ BT,
    bfu* __restrict__ Cb, int N, int K, float scale, int m0, int n0) {
  const int tid = threadIdx.x, lane = tid & 63, wave = tid >> 6;
  const int g = lane >> 4, c = lane & 15;
  const int wm = (wave >> 1) * 64, wn = (wave & 1) * 64;
  const int nt = K / 32;

  auto stage = [&](int buf, int kt) {
#pragma unroll
    for (int u = 0; u < 4; ++u) {
      int idx = wave * 4 + u;
      if (idx < 8) {
        int kg = idx & 3, rb = idx >> 2;
        gload16(&A[(size_t)(m0 + rb * 64 + lane) * K + kt + kg * 8], &As2[buf][kg][rb * 64][0]);
      } else {
        int kg = (idx - 8) & 3, rb = (idx - 8) >> 2;
        gload16(&BT[(size_t)(n0 + rb * 64 + lane) * K + kt + kg * 8], &Bs2[buf][kg][rb * 64][0]);
      }
    }
  };

  f32x4 acc[4][4] = {};
  stage(0, 0);
  for (int t = 0; t < nt; ++t) {
    __syncthreads();
    if (t + 1 < nt) stage((t + 1) & 1, (t + 1) * 32);
    const int b = t & 1;
    short8 af[4], bfr[4];
#pragma unroll
    for (int i = 0; i < 4; ++i) {
      af[i]  = *(const short8*)&As2[b][g][wm + i * 16 + c][0];
      bfr[i] = *(const short8*)&Bs2[b][g][wn + i * 16 + c][0];
    }
#pragma unroll
    for (int i = 0; i < 4; ++i)
#pragma unroll
      for (int j = 0; j < 4; ++j)
        acc[i][j] = __builtin_amdgcn_mfma_f32_16x16x32_bf16(af[i], bfr[j], acc[i][j], 0, 0, 0);
  }
#pragma unroll
  for (int i = 0; i < 4; ++i)
#pragma unroll
    for (int j = 0; j < 4; ++j) {
      int row = m0 + wm + i * 16 + g * 4;
      int col = n0 + wn + j * 16 + c;
#pragma unroll
      for (int r = 0; r < 4; ++r)
        Cb[(size_t)(row + r) * N + col] = f2bf(acc[i][j][r] * scale);
    }
}

// ---------------- 128x64 GEMM body [proven verbatim] ----------------
typedef bfu AsArr[2][4][128][8];
typedef bfu BsArr[2][4][64][8];

__device__ __forceinline__ void gemm_body(AsArr& As2, BsArr& Bs2,
    const bfu* __restrict__ A, const bfu* __restrict__ BT,
    bfu* __restrict__ Cb, float* __restrict__ Cf,
    int N, int K, float scale, int m0, int n0) {
  const int tid = threadIdx.x, lane = tid & 63, wave = tid >> 6;
  const int g = lane >> 4, c = lane & 15;
  const int wm = wave * 32;
  const int nt = K / 32;

  auto stage = [&](int buf, int kt) {
#pragma unroll
    for (int u = 0; u < 3; ++u) {
      int idx = wave * 3 + u;
      if (idx < 8) {
        int g2 = idx & 3, rb = idx >> 2;
        gload16(&A[(size_t)(m0 + rb * 64 + lane) * K + kt + g2 * 8], &As2[buf][g2][rb * 64][0]);
      } else {
        int g2 = idx - 8;
        gload16(&BT[(size_t)(n0 + lane) * K + kt + g2 * 8], &Bs2[buf][g2][0][0]);
      }
    }
  };

  f32x4 acc[2][4] = {};
  stage(0, 0);
  for (int t = 0; t < nt; ++t) {
    __syncthreads();
    if (t + 1 < nt) stage((t + 1) & 1, (t + 1) * 32);
    const int b = t & 1;
    short8 af[2], bfr[4];
#pragma unroll
    for (int i = 0; i < 2; ++i) af[i] = *(const short8*)&As2[b][g][wm + i * 16 + c][0];
#pragma unroll
    for (int j = 0; j < 4; ++j) bfr[j] = *(const short8*)&Bs2[b][g][j * 16 + c][0];
#pragma unroll
    for (int i = 0; i < 2; ++i)
#pragma unroll
      for (int j = 0; j < 4; ++j)
        acc[i][j] = __builtin_amdgcn_mfma_f32_16x16x32_bf16(af[i], bfr[j], acc[i][j], 0, 0, 0);
  }
#pragma unroll
  for (int i = 0; i < 2; ++i)
#pragma unroll
    for (int j = 0; j < 4; ++j) {
      int row = m0 + wm + i * 16 + g * 4;
      int col = n0 + j * 16 + c;
#pragma unroll
      for (int r = 0; r < 4; ++r) {
        float v = acc[i][j][r] * scale;
        if (Cb) Cb[(size_t)(row + r) * N + col] = f2bf(v);
        else    Cf[(size_t)(row + r) * N + col] = v;
      }
    }
}

// fused Q/K/V projections, BALANCED 512 blocks = exactly 2/CU [r21-proven]
__global__ __launch_bounds__(256) void gemm3_kernel(
    const bfu* __restrict__ xb, const bfu* __restrict__ WTq, bfu* __restrict__ Qb,
    const bfu* __restrict__ ctxb, const bfu* __restrict__ WTk, bfu* __restrict__ Kb,
    const bfu* __restrict__ WTv, bfu* __restrict__ Vtb) {
  __shared__ alignas(16) bfu As2[2][4][128][8];
  __shared__ alignas(16) bfu Bs2[2][4][128][8];
  int bid = blockIdx.x;
  if (bid < 128)
    gemm128_body(As2, Bs2, xb, WTq, Qb, 1024, 1024, 0.125f * LOG2E, (bid >> 3) * 128, (bid & 7) * 128);
  else if (bid < 256) {
    int r = bid - 128;
    gemm128_body(As2, Bs2, ctxb, WTk, Kb, 1024, 768, 1.0f, (r >> 3) * 128, (r & 7) * 128);
  } else {  // V^T = Wv^T @ ctx^T at 128x64: A = WTv (1024x768), BT = ctxb (2048x768)
    int r = bid - 256;                   // 0..255 -> (1024/128) x (2048/64)
    gemm_body(*(AsArr*)As2, *(BsArr*)Bs2, WTv, ctxb, Vtb, nullptr,
              2048, 768, 1.0f, (r >> 5) * 128, (r & 31) * 64);
  }
}

// ---------------- output projection: 64x64 tile, 2 waves, 512 blocks = 2/CU ----------------
// Same per-wave ratio as the proven 128x64 body (8 MFMA : 6 ds_read_b128 per
// K-step) but 2 blocks/CU -> one block's compute covers the other's barrier
// vmcnt drain (the r14-diagnosed stall, fully exposed at 1 block/CU before).
// XCD-grouped decode: each XCD owns 4 contiguous m-panels -> per-XCD reads
// (512KB A-panels + 2MB WTo) fit its 4MB L2.
typedef bfu T64[2][4][64][8];

__global__ __launch_bounds__(128) void gemmo_kernel(const bfu* __restrict__ AO,
                                                    const bfu* __restrict__ WTo,
                                                    float* __restrict__ out) {
  __shared__ alignas(16) bfu As2[2][4][64][8];
  __shared__ alignas(16) bfu Bs2[2][4][64][8];
  const int tid = threadIdx.x, lane = tid & 63, wave = tid >> 6;  // wave 0..1
  const int g = lane >> 4, c = lane & 15;
  const int bid = blockIdx.x;
  const int xcd = bid & 7, slot = bid >> 3;
  const int m0 = (xcd * 4 + (slot >> 4)) * 64;   // bijective: 4 m-panels per XCD
  const int n0 = (slot & 15) * 64;
  const int wm = wave * 32;
  const int K = 1024, N = 1024, nt = 32;

  auto stage = [&](int buf, int kt) {
#pragma unroll
    for (int u = 0; u < 4; ++u) {
      int idx = wave * 4 + u;                    // 0..7
      if (idx < 4)
        gload16(&AO[(size_t)(m0 + lane) * K + kt + idx * 8], &As2[buf][idx][lane][0]);
      else
        gload16(&WTo[(size_t)(n0 + lane) * K + kt + (idx - 4) * 8], &Bs2[buf][idx - 4][lane][0]);
    }
  };

  f32x4 acc[2][4] = {};
  stage(0, 0);
  for (int t = 0; t < nt; ++t) {
    __syncthreads();
    if (t + 1 < nt) stage((t + 1) & 1, (t + 1) * 32);
    const int b = t & 1;
    short8 af[2], bfr[4];
#pragma unroll
    for (int i = 0; i < 2; ++i) af[i] = *(const short8*)&As2[b][g][wm + i * 16 + c][0];
#pragma unroll
    for (int j = 0; j < 4; ++j) bfr[j] = *(const short8*)&Bs2[b][g][j * 16 + c][0];
#pragma unroll
    for (int i = 0; i < 2; ++i)
#pragma unroll
      for (int j = 0; j < 4; ++j)
        acc[i][j] = __builtin_amdgcn_mfma_f32_16x16x32_bf16(af[i], bfr[j], acc[i][j], 0, 0, 0);
  }
#pragma unroll
  for (int i = 0; i < 2; ++i)
#pragma unroll
    for (int j = 0; j < 4; ++j) {
      int row = m0 + wm + i * 16 + g * 4;
      int col = n0 + j * 16 + c;
#pragma unroll
      for (int r = 0; r < 4; ++r)
        out[(size_t)(row + r) * N + col] = acc[i][j][r];
    }
}

// ---------------- flash attention [r18 CHAMPION, verbatim] ----------------
// Q [2048][1024] bf16 (pre-scaled 0.125*log2e), Kmat [2048 kv][1024], Vt [1024 d][2048 kv]
__global__ __launch_bounds__(256) void attn_kernel(
    const bfu* __restrict__ Q, const bfu* __restrict__ Kmat,
    const bfu* __restrict__ Vt, bfu* __restrict__ O) {
  __shared__ alignas(16) bfu Ks[3][8][64][8];   // [buf][dgroup][kv][8]
  __shared__ alignas(16) bfu Vs[3][8][64][8];   // [buf][kvgroup8][d][8]
  __shared__ alignas(16) bfu Ps[2][64][72];     // double-buffered P
  const int tid = threadIdx.x, wave = tid >> 6, lane = tid & 63;
  const int g = lane >> 4, c = lane & 15;
  const int bid = blockIdx.x;
  const int xcd = bid & 7, slot = bid >> 3;
  const int h = xcd + 8 * (slot >> 5);          // bijective: 2 heads/XCD
  const int qblk = (slot & 31) * 64;
  const int col0 = h * 64;

  short8 qf[4][2];
#pragma unroll
  for (int qt = 0; qt < 4; ++qt) {
    qf[qt][0] = *(const short8*)&Q[(size_t)(qblk + qt * 16 + c) * 1024 + col0 + g * 8];
    qf[qt][1] = *(const short8*)&Q[(size_t)(qblk + qt * 16 + c) * 1024 + col0 + 32 + g * 8];
  }

  short8 ones;
#pragma unroll
  for (int e = 0; e < 8; ++e) ones[e] = (short)0x3F80;  // bf16 1.0

  f32x4 o_acc[4] = {};
  f32x4 lacc = {};

  auto stage = [&](int buf, int kv0) {   // 4 gload16/wave [proven]
#pragma unroll
    for (int u = 0; u < 4; ++u) {
      int idx = wave * 4 + u;
      if (idx < 8)
        gload16(&Kmat[(size_t)(kv0 + lane) * 1024 + col0 + idx * 8], &Ks[buf][idx][0][0]);
      else
        gload16(&Vt[(size_t)(col0 + lane) * 2048 + kv0 + (idx - 8) * 8], &Vs[buf][idx - 8][0][0]);
    }
  };

  // QK-split: wave w computes S[all 64 q][kv chunk 16w..16w+15] -> Ps[pb]
  auto qk_exp = [&](int bQ, int pb) {
    short8 kf0 = *(const short8*)&Ks[bQ][g][wave * 16 + c][0];
    short8 kf1 = *(const short8*)&Ks[bQ][4 + g][wave * 16 + c][0];
    f32x4 s[4] = {};
    __builtin_amdgcn_s_setprio(1);
#pragma unroll
    for (int qt = 0; qt < 4; ++qt) {
      s[qt] = __builtin_amdgcn_mfma_f32_16x16x32_bf16(qf[qt][0], kf0, s[qt], 0, 0, 0);
      s[qt] = __builtin_amdgcn_mfma_f32_16x16x32_bf16(qf[qt][1], kf1, s[qt], 0, 0, 0);
    }
    __builtin_amdgcn_s_setprio(0);
    // P = 2^S via raw v_exp_f32 (log2e folded into Q) -- exactly exp(S_true)
#pragma unroll
    for (int qt = 0; qt < 4; ++qt)
#pragma unroll
      for (int j = 0; j < 4; ++j)
        Ps[pb][qt * 16 + g * 4 + j][wave * 16 + c] =
            f2bf(__builtin_amdgcn_exp2f(s[qt][j]));
  };

  // PV: wave w owns q-subtile w [proven indexing]
  auto pv = [&](int pb, int vb) {
    __builtin_amdgcn_s_setprio(1);
#pragma unroll
    for (int kc = 0; kc < 2; ++kc) {
      short8 pf = *(const short8*)&Ps[pb][wave * 16 + c][kc * 32 + g * 8];
      lacc = __builtin_amdgcn_mfma_f32_16x16x32_bf16(pf, ones, lacc, 0, 0, 0);
#pragma unroll
      for (int fd = 0; fd < 4; ++fd) {
        short8 vf = *(const short8*)&Vs[vb][kc * 4 + g][fd * 16 + c][0];
        o_acc[fd] = __builtin_amdgcn_mfma_f32_16x16x32_bf16(pf, vf, o_acc[fd], 0, 0, 0);
      }
    }
    __builtin_amdgcn_s_setprio(0);
  };

  stage(0, 0);
  __syncthreads();           // drains stage(0) + qf loads
  stage(1, 64);
  qk_exp(0, 0);
  __syncthreads();
  for (int t = 1; t < 32; ++t) {
    stage((t + 1) % 3, ((t + 1) & 31) * 64);   // t=31 wraps: redundant, never read
    qk_exp(t % 3, t & 1);
    pv((t - 1) & 1, (t - 1) % 3);              // exp VALU overlaps PV MFMA
    __syncthreads();                           // single barrier: Ps handoff + buffers
  }
  pv(1, 1);                                    // PV(31): Ps[31&1], Vs[31%3]

  const int q0 = qblk + wave * 16;
#pragma unroll
  for (int fd = 0; fd < 4; ++fd)
#pragma unroll
    for (int j = 0; j < 4; ++j) {
      float v = o_acc[fd][j] / lacc[j];
      O[(size_t)(q0 + g * 4 + j) * 1024 + col0 + fd * 16 + c] = f2bf(v);
    }
}

extern "C" void kernel_launch(void* const* d_in, const int* in_sizes, int n_in,
                              void* d_out, int out_size, void* d_ws, size_t ws_size,
                              hipStream_t stream) {
  const float* x   = (const float*)d_in[0];
  const float* ctx = (const float*)d_in[1];
  const float* Wq  = (const float*)d_in[2];
  const float* Wk  = (const float*)d_in[3];
  const float* Wv  = (const float*)d_in[4];
  const float* Wo  = (const float*)d_in[5];
  float* out = (float*)d_out;

  // ws: 10.25M bf16 elems (ws_size ~268MB per r18 fill trace -- ample).
  bfu* ws   = (bfu*)d_ws;
  bfu* xb   = ws;                        // 2M    (reused as attn-out)
  bfu* WTk  = xb + 2048 * 1024;          // 0.75M
  bfu* WTv  = WTk + 1024 * 768;          // 0.75M
  bfu* WTo  = WTv + 1024 * 768;          // 1M
  bfu* Qb   = WTo + 1024 * 1024;         // 2M
  bfu* Kb   = Qb + 2048 * 1024;          // 2M
  bfu* Vtb  = Kb + 2048 * 1024;          // 2M
  // d_out (8 MB f32) doubles as scratch for WTq + ctxb; both fully rewritten
  // each call before use, and gemmo overwrites all of d_out at the end.
  bfu* WTq  = (bfu*)d_out;               // 1M
  bfu* ctxb = WTq + 1024 * 1024;         // 1.5M  (total 5 MB <= 8 MB)

  dim3 blk(256);
  prep_kernel<<<5376, blk, 0, stream>>>(x, ctx, Wq, Wk, Wv, Wo, xb, ctxb, WTq, WTk, WTv, WTo);
  gemm3_kernel<<<512, blk, 0, stream>>>(xb, WTq, Qb, ctxb, WTk, Kb, WTv, Vtb);
  attn_kernel<<<512, blk, 0, stream>>>(Qb, Kb, Vtb, xb);
  gemmo_kernel<<<512, dim3(128), 0, stream>>>(xb, WTo, out);
}